// Round 5
// baseline (4028.754 us; speedup 1.0000x reference)
//
#include <hip/hip_runtime.h>

// Sinkhorn EMD, B=8, N=2048, eps=0.005, 50 iters.
// R5: occupancy attack. 512 blocks x 1024 thr = 2 blocks/CU = 32 waves/CU
// (8/SIMD, HW max) to hide exp/DS latency that capped R1/R3/R4 at ~2
// elem/cyc/CU. LDS trimmed to ~75KB/block (2 resident): float4 G with
// .w = -|g|^2/K (pass-invariant) + single b32 potential column sa[].
// VGPR capped via __launch_bounds__(1024,8). Per-batch monotonic barrier
// (validated R3/R4), relaxed polls + one trailing acquire fence.
// Passes 0..5 exact online-rescale LSE; 6..99 fixed-shift (validated).

#define BB 8
#define NN 2048
#define NPASS 100
#define ONLINE_PASSES 6
#define RPW 8
#define GRID_BLOCKS 512
#define BLOCKS_PER_BATCH 64
#define TPB 1024

constexpr float EPSV = 0.005f;
constexpr float KS   = EPSV * 0.69314718055994531f; // eps*ln2
constexpr float INVK = 1.0f / KS;
constexpr float C1V  = -EPSV * 7.6246189861593985f; // eps*log(1/2048)
constexpr float KQ4  = KS * 0.25f;        // |g|^2/K = KQ4 * |G|^2
constexpr float TWOI = 2.0f * INVK;       // G = TWOI * g

__device__ __forceinline__ float fexp2(float x) { return __builtin_amdgcn_exp2f(x); }
__device__ __forceinline__ float flog2(float x) { return __builtin_amdgcn_logf(x); }

__device__ __forceinline__ void barrier_sync(int* ctr, int target) {
    __syncthreads();
    if (threadIdx.x == 0) {
        __threadfence();   // release: make our pout/partials visible
        __hip_atomic_fetch_add(ctr, 1, __ATOMIC_RELAXED, __HIP_MEMORY_SCOPE_AGENT);
        while (__hip_atomic_load(ctr, __ATOMIC_RELAXED, __HIP_MEMORY_SCOPE_AGENT) < target) {
            __builtin_amdgcn_s_sleep(2);
        }
        __threadfence();   // acquire: invalidate so we see others' pout
    }
    __syncthreads();
}

__global__ void __launch_bounds__(TPB, 8) emd_persist(
    const float* __restrict__ preds, const float* __restrict__ gts,
    float* __restrict__ fpot, float* __restrict__ gpot,
    float* __restrict__ partials, int* __restrict__ bctr, int* __restrict__ gctr,
    float* __restrict__ out)
{
    __shared__ float4 sjall[2 * NN];   // {Gx,Gy,Gz, -|g|^2/K}; 0=gts 1=preds
    __shared__ float  sa[NN];          // active-side potential column pot/K
    __shared__ float  smS[32][4];      // [row-in-block][quarter] partial s
    __shared__ float  smM[32][4];      // online-path partial m
    __shared__ float  wred[16];

    const int blk  = blockIdx.x;
    const int b    = blk >> 6;                 // 64 blocks per batch
    const int rb   = blk & 63;                 // 32 rows per block
    const int wave = threadIdx.x >> 6;
    const int lane = threadIdx.x & 63;
    const int grp  = wave & 3;                 // row group (8 rows)
    const int colq = wave >> 2;                // column quarter (512 cols)
    const int row0 = rb * 32 + grp * RPW;
    const int cb   = colq << 9;

    const float* pb  = preds + (size_t)b * NN * 3;
    const float* gbp = gts   + (size_t)b * NN * 3;
    float* fb = fpot + (size_t)b * NN;
    float* gb = gpot + (size_t)b * NN;
    int*   bar = bctr + b * 32;

    // one-time staging: G = 2g/K, .w = -|g|^2/K  (pass-invariant)
    for (int t = threadIdx.x; t < NN; t += TPB) {
        float gx = gbp[3*t], gy = gbp[3*t+1], gz = gbp[3*t+2];
        float Gx = gx*TWOI, Gy = gy*TWOI, Gz = gz*TWOI;
        sjall[t] = make_float4(Gx, Gy, Gz, -KQ4*(Gx*Gx+Gy*Gy+Gz*Gz));
        float qx = pb[3*t], qy = pb[3*t+1], qz = pb[3*t+2];
        float Qx = qx*TWOI, Qy = qy*TWOI, Qz = qz*TWOI;
        sjall[NN+t] = make_float4(Qx, Qy, Qz, -KQ4*(Qx*Qx+Qy*Qy+Qz*Qz));
    }

#pragma unroll 1
    for (int pass = 0; pass < NPASS; ++pass) {
        const int odd = pass & 1;
        const float* rpts = odd ? gbp : pb;
        const float* pin  = odd ? fb  : gb;
        float*       pout = odd ? gb  : fb;
        const int    sjo  = odd ? NN  : 0;

        // per-pass staging: potential column only (conflict-free b32)
        for (int t = threadIdx.x; t < NN; t += TPB)
            sa[t] = pin[t] * INVK;

        float px[RPW], py[RPW], pz[RPW], pn[RPW], M[RPW], s[RPW];
#pragma unroll
        for (int r = 0; r < RPW; ++r) {
            int i = row0 + r;
            px[r] = rpts[3*i]; py[r] = rpts[3*i+1]; pz[r] = rpts[3*i+2];
            pn[r] = px[r]*px[r] + py[r]*py[r] + pz[r]*pz[r];
            s[r]  = 0.f;
        }
        if (pass >= ONLINE_PASSES) {
#pragma unroll
            for (int r = 0; r < RPW; ++r) {
                float prev = pout[row0 + r];      // own block wrote it
                M[r] = (C1V + pn[r] - prev) * INVK;
            }
        }
        __syncthreads();

        if (pass < ONLINE_PASSES) {
            float m[RPW];
#pragma unroll
            for (int r = 0; r < RPW; ++r) m[r] = -1e30f;
#pragma unroll 4
            for (int c = 0; c < 8; ++c) {
                float4 d = sjall[sjo + cb + c*64 + lane];
                float aw = d.w + sa[cb + c*64 + lane];
#pragma unroll
                for (int r = 0; r < RPW; ++r) {
                    float x  = fmaf(px[r], d.x, fmaf(py[r], d.y, fmaf(pz[r], d.z, aw)));
                    float mn = fmaxf(m[r], x);
                    s[r] = fmaf(s[r], fexp2(m[r]-mn), fexp2(x-mn));
                    m[r] = mn;
                }
            }
#pragma unroll
            for (int r = 0; r < RPW; ++r) {
                float mm = m[r], ss = s[r];
                for (int off = 1; off < 64; off <<= 1) {
                    float mo = __shfl_xor(mm, off, 64);
                    float so = __shfl_xor(ss, off, 64);
                    float mn = fmaxf(mm, mo);
                    ss = fmaf(ss, fexp2(mm-mn), so * fexp2(mo-mn));
                    mm = mn;
                }
                m[r] = mm; s[r] = ss;
            }
            if (lane == 0) {
#pragma unroll
                for (int r = 0; r < RPW; ++r) {
                    smM[grp*RPW + r][colq] = m[r];
                    smS[grp*RPW + r][colq] = s[r];
                }
            }
            __syncthreads();
            if (colq == 0 && lane == 0) {
#pragma unroll
                for (int r = 0; r < RPW; ++r) {
                    float mm = smM[grp*RPW + r][0], ss = smS[grp*RPW + r][0];
#pragma unroll
                    for (int q = 1; q < 4; ++q) {
                        float mo = smM[grp*RPW + r][q], so = smS[grp*RPW + r][q];
                        float mn = fmaxf(mm, mo);
                        ss = fmaf(ss, fexp2(mm-mn), so * fexp2(mo-mn));
                        mm = mn;
                    }
                    pout[row0+r] = C1V + pn[r] - KS * (mm + flog2(fmaxf(ss, 1e-37f)));
                }
            }
        } else {
            // fixed-shift: 1 exp/elem, M identical across the 4 quarter waves
#pragma unroll 4
            for (int c = 0; c < 8; ++c) {
                float4 d = sjall[sjo + cb + c*64 + lane];
                float aw = d.w + sa[cb + c*64 + lane];
#pragma unroll
                for (int r = 0; r < RPW; ++r) {
                    float x = fmaf(px[r], d.x, fmaf(py[r], d.y, fmaf(pz[r], d.z, aw)));
                    s[r] += fexp2(fminf(x - M[r], 100.f));
                }
            }
#pragma unroll
            for (int r = 0; r < RPW; ++r) {
                float ss = s[r];
                for (int off = 1; off < 64; off <<= 1) ss += __shfl_xor(ss, off, 64);
                s[r] = ss;
            }
            if (lane == 0) {
#pragma unroll
                for (int r = 0; r < RPW; ++r) smS[grp*RPW + r][colq] = s[r];
            }
            __syncthreads();
            if (colq == 0 && lane == 0) {
#pragma unroll
                for (int r = 0; r < RPW; ++r) {
                    float st = smS[grp*RPW+r][0] + smS[grp*RPW+r][1]
                             + smS[grp*RPW+r][2] + smS[grp*RPW+r][3];
                    pout[row0+r] = C1V + pn[r] - KS * (M[r] + flog2(fmaxf(st, 1e-37f)));
                }
            }
        }
        barrier_sync(bar, BLOCKS_PER_BATCH * (pass + 1));
    }

    // ---- dis: sum P*C over cols = gts (side 0) with final g potential ----
    for (int t = threadIdx.x; t < NN; t += TPB)
        sa[t] = gb[t] * INVK;

    float px[RPW], py[RPW], pz[RPW], pn[RPW], bb2[RPW], acc[RPW];
#pragma unroll
    for (int r = 0; r < RPW; ++r) {
        int i = row0 + r;
        px[r] = pb[3*i]; py[r] = pb[3*i+1]; pz[r] = pb[3*i+2];
        pn[r] = px[r]*px[r] + py[r]*py[r] + pz[r]*pz[r];
        bb2[r] = (fb[i] - pn[r]) * INVK;
        acc[r] = 0.f;
    }
    __syncthreads();
#pragma unroll 4
    for (int c = 0; c < 8; ++c) {
        float4 d = sjall[cb + c*64 + lane];
        float aw = d.w + sa[cb + c*64 + lane];
        float gn = -KS * d.w;                 // |g|^2
#pragma unroll
        for (int r = 0; r < RPW; ++r) {
            float dot = fmaf(px[r], d.x, fmaf(py[r], d.y, pz[r]*d.z));
            float y   = dot + aw + bb2[r];    // log2 P
            float e   = fexp2(fminf(y, 80.f));
            float Cc  = fmaf(-KS, dot, pn[r] + gn);
            acc[r] = fmaf(e, Cc, acc[r]);
        }
    }
    float tot = 0.f;
#pragma unroll
    for (int r = 0; r < RPW; ++r) tot += acc[r];
    for (int off = 1; off < 64; off <<= 1) tot += __shfl_xor(tot, off, 64);
    if (lane == 0) smS[grp*RPW][colq] = 0.f;  // (placeholder keeps layout warm)
    if (lane == 0) smS[wave & 31][wave >> 5] = tot;  // 16 waves -> [0..15][0]
    __syncthreads();
    if (threadIdx.x == 0) {
        float v = 0.f;
        for (int w = 0; w < 16; ++w) v += smS[w][0];
        partials[blk] = v;
    }

    barrier_sync(gctr, GRID_BLOCKS);

    if (blk == 0) {
        float v = (threadIdx.x < GRID_BLOCKS) ? partials[threadIdx.x] : 0.f;
        for (int off = 1; off < 64; off <<= 1) v += __shfl_xor(v, off, 64);
        if (lane == 0) wred[wave] = v;
        __syncthreads();
        if (threadIdx.x == 0) {
            float t2 = 0.f;
            for (int w = 0; w < 16; ++w) t2 += wred[w];
            out[0] = t2 * (1.0f / BB);
        }
    }
}

extern "C" void kernel_launch(void* const* d_in, const int* in_sizes, int n_in,
                              void* d_out, int out_size, void* d_ws, size_t ws_size,
                              hipStream_t stream) {
    const float* preds = (const float*)d_in[0];
    const float* gts   = (const float*)d_in[1];
    float* fp       = (float*)d_ws;                   // [B*N]
    float* gp       = fp + BB * NN;                   // [B*N]
    float* partials = gp + BB * NN;                   // [512]
    int*   bctr     = (int*)(partials + GRID_BLOCKS); // 8 x 32 ints
    int*   gctr     = bctr + BB * 32;                 // [32]
    float* out      = (float*)d_out;

    size_t zbytes = (size_t)(2 * BB * NN + GRID_BLOCKS) * sizeof(float)
                  + (size_t)(BB * 32 + 32) * sizeof(int);
    hipMemsetAsync(d_ws, 0, zbytes, stream);

    emd_persist<<<dim3(GRID_BLOCKS), dim3(TPB), 0, stream>>>(
        preds, gts, fp, gp, partials, bctr, gctr, out);
}

// Round 6
// 1154.216 us; speedup vs baseline: 3.4905x; 3.4905x over previous
//
#include <hip/hip_runtime.h>

// Sinkhorn EMD, B=8, N=2048, eps=0.005, 50 iters.
// R6: kill per-pass coherence flushes. All cross-block data (potentials,
// partials, barrier counters) uses fine-grained agent-scope atomics
// (sc0 sc1 -> Infinity Cache, the coherence point). No __threadfence
// anywhere: __syncthreads before the arrival-add drains vmcnt, so sc1
// stores are IC-visible before the counter bump. Proven R4 shape:
// 256 blocks x 1024 thr (1/CU, 16 waves), RPW=8, column-split halves,
// VGPR budget 128 (R5's launch_bounds(,8) spill disaster reverted).
// Row log-sums persist in LDS (sPrevL) -> fixed-shift M and dis bb2 need
// no global re-read. Passes 0..5 exact online LSE; 6..99 fixed-shift
// (M = own previous log-sum, clamp +100) — numerics validated R3-R5.

#define BB 8
#define NN 2048
#define NPASS 100
#define ONLINE_PASSES 6
#define RPW 8
#define GRID_BLOCKS 256
#define BLOCKS_PER_BATCH 32
#define TPB 1024

constexpr float EPSV = 0.005f;
constexpr float KS   = EPSV * 0.69314718055994531f; // eps*ln2
constexpr float INVK = 1.0f / KS;
constexpr float C1V  = -EPSV * 7.6246189861593985f; // eps*log(1/2048)
constexpr float KQ4  = KS * 0.25f;        // |g|^2/K = KQ4 * |G|^2
constexpr float TWOI = 2.0f * INVK;       // G = TWOI * g

__device__ __forceinline__ float fexp2(float x) { return __builtin_amdgcn_exp2f(x); }
__device__ __forceinline__ float flog2(float x) { return __builtin_amdgcn_logf(x); }

// IC-coherent accessors (bypass L1/L2; no flushes needed)
__device__ __forceinline__ float cohLoad(const float* p) {
    return __hip_atomic_load(p, __ATOMIC_RELAXED, __HIP_MEMORY_SCOPE_AGENT);
}
__device__ __forceinline__ void cohStore(float* p, float v) {
    __hip_atomic_store(p, v, __ATOMIC_RELAXED, __HIP_MEMORY_SCOPE_AGENT);
}

// Monotonic barrier, fence-free: __syncthreads drains vmcnt (sc1 stores
// reach IC) before the arrival add; polls read the IC directly.
__device__ __forceinline__ void barrier_sync(int* ctr, int target) {
    __syncthreads();
    if (threadIdx.x == 0) {
        __hip_atomic_fetch_add(ctr, 1, __ATOMIC_RELAXED, __HIP_MEMORY_SCOPE_AGENT);
        while (__hip_atomic_load(ctr, __ATOMIC_RELAXED, __HIP_MEMORY_SCOPE_AGENT) < target) {
            __builtin_amdgcn_s_sleep(2);
        }
    }
    __syncthreads();
}

__global__ void __launch_bounds__(TPB, 4) emd_persist(
    const float* __restrict__ preds, const float* __restrict__ gts,
    float* __restrict__ fpot, float* __restrict__ gpot,
    float* __restrict__ partials, int* __restrict__ bctr, int* __restrict__ gctr,
    float* __restrict__ out)
{
    __shared__ float4 sjall[2 * NN];   // {Gx,Gy,Gz,-|g|^2/K}; 0=gts 1=preds
    __shared__ float  sa[NN];          // active-side potential column pot/K
    __shared__ float  sPrevL[2][64];   // [side][row-in-block] last log-sum L
    __shared__ float  smS[64][2];      // [row][half] partial s
    __shared__ float  smM[64][2];      // online-path partial m
    __shared__ float  wred[16];

    const int blk  = blockIdx.x;
    const int b    = blk >> 5;                 // 32 blocks per batch
    const int rb   = blk & 31;                 // 64 rows per block
    const int wave = threadIdx.x >> 6;
    const int lane = threadIdx.x & 63;
    const int grp  = wave & 7;                 // row group (8 rows)
    const int half = wave >> 3;                // column half (1024 cols)
    const int row0 = rb * 64 + grp * RPW;
    const int cb   = half << 10;

    const float* pb  = preds + (size_t)b * NN * 3;
    const float* gbp = gts   + (size_t)b * NN * 3;
    float* fb = fpot + (size_t)b * NN;
    float* gb = gpot + (size_t)b * NN;
    int*   bar = bctr + b * 32;

    // one-time LDS staging: G = 2g/K, .w = -|g|^2/K (pass-invariant)
    for (int t = threadIdx.x; t < NN; t += TPB) {
        float gx = gbp[3*t], gy = gbp[3*t+1], gz = gbp[3*t+2];
        float Gx = gx*TWOI, Gy = gy*TWOI, Gz = gz*TWOI;
        sjall[t] = make_float4(Gx, Gy, Gz, -KQ4*(Gx*Gx+Gy*Gy+Gz*Gz));
        float qx = pb[3*t], qy = pb[3*t+1], qz = pb[3*t+2];
        float Qx = qx*TWOI, Qy = qy*TWOI, Qz = qz*TWOI;
        sjall[NN+t] = make_float4(Qx, Qy, Qz, -KQ4*(Qx*Qx+Qy*Qy+Qz*Qz));
    }

#pragma unroll 1
    for (int pass = 0; pass < NPASS; ++pass) {
        const int odd = pass & 1;
        const float* rpts = odd ? gbp : pb;
        const float* pin  = odd ? fb  : gb;
        float*       pout = odd ? gb  : fb;
        const int    sjo  = odd ? NN  : 0;

        // stage potential column through the IC (coherent, no flush)
        for (int t = threadIdx.x; t < NN; t += TPB)
            sa[t] = cohLoad(&pin[t]) * INVK;

        float px[RPW], py[RPW], pz[RPW], pn[RPW], M[RPW], s[RPW];
#pragma unroll
        for (int r = 0; r < RPW; ++r) {
            int i = row0 + r;
            px[r] = rpts[3*i]; py[r] = rpts[3*i+1]; pz[r] = rpts[3*i+2];
            pn[r] = px[r]*px[r] + py[r]*py[r] + pz[r]*pz[r];
            s[r]  = 0.f;
        }
        if (pass >= ONLINE_PASSES) {
#pragma unroll
            for (int r = 0; r < RPW; ++r)
                M[r] = sPrevL[odd][grp*RPW + r];   // own row's last log-sum
        }
        __syncthreads();

        if (pass < ONLINE_PASSES) {
            float m[RPW];
#pragma unroll
            for (int r = 0; r < RPW; ++r) m[r] = -1e30f;
#pragma unroll 4
            for (int c = 0; c < 16; ++c) {
                float4 d = sjall[sjo + cb + c*64 + lane];
                float aw = d.w + sa[cb + c*64 + lane];
#pragma unroll
                for (int r = 0; r < RPW; ++r) {
                    float x  = fmaf(px[r], d.x, fmaf(py[r], d.y, fmaf(pz[r], d.z, aw)));
                    float mn = fmaxf(m[r], x);
                    s[r] = fmaf(s[r], fexp2(m[r]-mn), fexp2(x-mn));
                    m[r] = mn;
                }
            }
#pragma unroll
            for (int r = 0; r < RPW; ++r) {
                float mm = m[r], ss = s[r];
                for (int off = 1; off < 64; off <<= 1) {
                    float mo = __shfl_xor(mm, off, 64);
                    float so = __shfl_xor(ss, off, 64);
                    float mn = fmaxf(mm, mo);
                    ss = fmaf(ss, fexp2(mm-mn), so * fexp2(mo-mn));
                    mm = mn;
                }
                m[r] = mm; s[r] = ss;
            }
            if (lane == 0) {
#pragma unroll
                for (int r = 0; r < RPW; ++r) {
                    smM[grp*RPW + r][half] = m[r];
                    smS[grp*RPW + r][half] = s[r];
                }
            }
            __syncthreads();
            if (half == 1 && lane == 0) {
#pragma unroll
                for (int r = 0; r < RPW; ++r) {
                    float mo = smM[grp*RPW + r][0], so = smS[grp*RPW + r][0];
                    float mn = fmaxf(m[r], mo);
                    float st = fmaf(s[r], fexp2(m[r]-mn), so * fexp2(mo-mn));
                    float L  = mn + flog2(fmaxf(st, 1e-37f));
                    sPrevL[odd][grp*RPW + r] = L;
                    cohStore(&pout[row0+r], C1V + pn[r] - KS * L);
                }
            }
        } else {
            // fixed-shift: 1 exp/elem, M identical across both halves
#pragma unroll 4
            for (int c = 0; c < 16; ++c) {
                float4 d = sjall[sjo + cb + c*64 + lane];
                float aw = d.w + sa[cb + c*64 + lane];
#pragma unroll
                for (int r = 0; r < RPW; ++r) {
                    float x = fmaf(px[r], d.x, fmaf(py[r], d.y, fmaf(pz[r], d.z, aw)));
                    s[r] += fexp2(fminf(x - M[r], 100.f));
                }
            }
#pragma unroll
            for (int r = 0; r < RPW; ++r) {
                float ss = s[r];
                for (int off = 1; off < 64; off <<= 1) ss += __shfl_xor(ss, off, 64);
                s[r] = ss;
            }
            if (lane == 0) {
#pragma unroll
                for (int r = 0; r < RPW; ++r) smS[grp*RPW + r][half] = s[r];
            }
            __syncthreads();
            if (half == 1 && lane == 0) {
#pragma unroll
                for (int r = 0; r < RPW; ++r) {
                    float st = s[r] + smS[grp*RPW + r][0];
                    float L  = M[r] + flog2(fmaxf(st, 1e-37f));
                    sPrevL[odd][grp*RPW + r] = L;
                    cohStore(&pout[row0+r], C1V + pn[r] - KS * L);
                }
            }
        }
        barrier_sync(bar, BLOCKS_PER_BATCH * (pass + 1));
    }

    // ---- dis: sum P*C over cols = gts (side 0), final g potential ----
    for (int t = threadIdx.x; t < NN; t += TPB)
        sa[t] = cohLoad(&gb[t]) * INVK;

    float px[RPW], py[RPW], pz[RPW], pn[RPW], bb2[RPW], acc[RPW];
#pragma unroll
    for (int r = 0; r < RPW; ++r) {
        int i = row0 + r;
        px[r] = pb[3*i]; py[r] = pb[3*i+1]; pz[r] = pb[3*i+2];
        pn[r] = px[r]*px[r] + py[r]*py[r] + pz[r]*pz[r];
        // fb[i] = C1 + pn - K*L  ->  (fb[i]-pn)/K = C1/K - L  (L from LDS)
        bb2[r] = C1V * INVK - sPrevL[0][grp*RPW + r];
        acc[r] = 0.f;
    }
    __syncthreads();
#pragma unroll 4
    for (int c = 0; c < 16; ++c) {
        float4 d = sjall[cb + c*64 + lane];
        float aw = d.w + sa[cb + c*64 + lane];
        float gn = -KS * d.w;                 // |g|^2
#pragma unroll
        for (int r = 0; r < RPW; ++r) {
            float dot = fmaf(px[r], d.x, fmaf(py[r], d.y, pz[r]*d.z));
            float y   = dot + aw + bb2[r];    // log2 P
            float e   = fexp2(fminf(y, 80.f));
            float Cc  = fmaf(-KS, dot, pn[r] + gn);
            acc[r] = fmaf(e, Cc, acc[r]);
        }
    }
    float tot = 0.f;
#pragma unroll
    for (int r = 0; r < RPW; ++r) tot += acc[r];
    for (int off = 1; off < 64; off <<= 1) tot += __shfl_xor(tot, off, 64);
    if (lane == 0) wred[wave] = tot;
    __syncthreads();
    if (threadIdx.x == 0) {
        float v = 0.f;
        for (int w = 0; w < 16; ++w) v += wred[w];
        cohStore(&partials[blk], v);
    }

    barrier_sync(gctr, GRID_BLOCKS);

    if (blk == 0) {
        float v = (threadIdx.x < GRID_BLOCKS) ? cohLoad(&partials[threadIdx.x]) : 0.f;
        for (int off = 1; off < 64; off <<= 1) v += __shfl_xor(v, off, 64);
        if (lane == 0) wred[wave] = v;
        __syncthreads();
        if (threadIdx.x == 0) {
            float t2 = 0.f;
            for (int w = 0; w < 16; ++w) t2 += wred[w];
            out[0] = t2 * (1.0f / BB);
        }
    }
}

extern "C" void kernel_launch(void* const* d_in, const int* in_sizes, int n_in,
                              void* d_out, int out_size, void* d_ws, size_t ws_size,
                              hipStream_t stream) {
    const float* preds = (const float*)d_in[0];
    const float* gts   = (const float*)d_in[1];
    float* fp       = (float*)d_ws;                   // [B*N]
    float* gp       = fp + BB * NN;                   // [B*N]
    float* partials = gp + BB * NN;                   // [256]
    int*   bctr     = (int*)(partials + GRID_BLOCKS); // 8 x 32 ints
    int*   gctr     = bctr + BB * 32;                 // [32]
    float* out      = (float*)d_out;

    size_t zbytes = (size_t)(2 * BB * NN + GRID_BLOCKS) * sizeof(float)
                  + (size_t)(BB * 32 + 32) * sizeof(int);
    hipMemsetAsync(d_ws, 0, zbytes, stream);

    emd_persist<<<dim3(GRID_BLOCKS), dim3(TPB), 0, stream>>>(
        preds, gts, fp, gp, partials, bctr, gctr, out);
}